// Round 4
// baseline (28.622 us; speedup 1.0000x reference)
//
#include <hip/hip_runtime.h>

// RoPE: x (B=8, S=16384, D=128) f32, cos/sin tables (16384, 64) f32,
// token_positions (16384,) i32. Interleaved pair layout:
// out[2i]   = cos[i]*x[2i] - sin[i]*x[2i+1]
// out[2i+1] = sin[i]*x[2i] + cos[i]*x[2i+1]
//
// 2-way batch-folded unroll: thread handles float4 t and t + N/2.
// N/2 = 4 full batches, so both share (s, j) -> one cos/sin table read
// serves two outputs, and two dwordx4 loads are in flight per thread.

typedef float f32x4 __attribute__((ext_vector_type(4)));
typedef float f32x2 __attribute__((ext_vector_type(2)));

#define S_LEN 16384
#define DK    128
#define NF4_PER_ROW (DK / 4)       // 32 float4 per row
#define HALF_F4 (8 / 2 * S_LEN * NF4_PER_ROW)  // 4 batches of float4s = 2,097,152

__global__ __launch_bounds__(256) void rope_f32_kernel(
    const f32x4* __restrict__ x,
    const f32x2* __restrict__ cos_tab,   // rows of 64 f32 = 32 float2
    const f32x2* __restrict__ sin_tab,
    const int*   __restrict__ tok_pos,
    f32x4*       __restrict__ out)
{
    const int t   = blockIdx.x * blockDim.x + threadIdx.x;  // 0 .. HALF_F4-1
    const int j   = t & (NF4_PER_ROW - 1);     // float4 index within row
    const int row = t >> 5;                    // b*S + s (b in 0..3)
    const int s   = row & (S_LEN - 1);
    const int pos = tok_pos[s];

    const f32x2 c  = cos_tab[pos * (DK / 4) + j];  // 2 pairs -> 2 cos
    const f32x2 sn = sin_tab[pos * (DK / 4) + j];
    const f32x4 v0 = x[t];
    const f32x4 v1 = x[t + HALF_F4];

    f32x4 o0, o1;
    o0.x = c.x * v0.x - sn.x * v0.y;
    o0.y = sn.x * v0.x + c.x * v0.y;
    o0.z = c.y * v0.z - sn.y * v0.w;
    o0.w = sn.y * v0.z + c.y * v0.w;

    o1.x = c.x * v1.x - sn.x * v1.y;
    o1.y = sn.x * v1.x + c.x * v1.y;
    o1.z = c.y * v1.z - sn.y * v1.w;
    o1.w = sn.y * v1.z + c.y * v1.w;

    out[t]           = o0;
    out[t + HALF_F4] = o1;
}

extern "C" void kernel_launch(void* const* d_in, const int* in_sizes, int n_in,
                              void* d_out, int out_size, void* d_ws, size_t ws_size,
                              hipStream_t stream) {
    const f32x4* x   = (const f32x4*)d_in[0];
    const f32x2* ct  = (const f32x2*)d_in[1];
    const f32x2* st  = (const f32x2*)d_in[2];
    const int*   tp  = (const int*)d_in[3];
    f32x4*       out = (f32x4*)d_out;

    const int n_half = out_size / 4 / 2;       // 2,097,152 threads
    const int block  = 256;
    const int grid   = (n_half + block - 1) / block;   // 8192

    rope_f32_kernel<<<grid, block, 0, stream>>>(x, ct, st, tp, out);
}

// Round 5
// 27.203 us; speedup vs baseline: 1.0522x; 1.0522x over previous
//
#include <hip/hip_runtime.h>

// RoPE: x (B=8, S=16384, D=128) f32, cos/sin tables (16384, 64) f32,
// token_positions (16384,) i32. Interleaved pair layout:
// out[2i]   = cos[i]*x[2i] - sin[i]*x[2i+1]
// out[2i+1] = sin[i]*x[2i] + cos[i]*x[2i+1]
//
// Persistent grid-stride (G11): 2048 blocks, stride = 524288 float4s
// = exactly ONE batch, so (s, j) and the cos/sin values are loop-
// invariant -> table loaded once, reused 8x. #pragma unroll 1 keeps
// each wave on a single dense memory front (R4 showed far-split
// per-thread access patterns regress).

typedef float f32x4 __attribute__((ext_vector_type(4)));
typedef float f32x2 __attribute__((ext_vector_type(2)));

#define S_LEN 16384
#define DK    128
#define NF4_PER_ROW (DK / 4)              // 32 float4 per row
#define N_F4  (8 * S_LEN * NF4_PER_ROW)   // 4,194,304
#define BLOCK 256
#define GRID  2048
#define STRIDE (GRID * BLOCK)             // 524,288 f4 = 1 batch
#define ITERS (N_F4 / STRIDE)             // 8

__global__ __launch_bounds__(BLOCK) void rope_f32_kernel(
    const f32x4* __restrict__ x,
    const f32x2* __restrict__ cos_tab,   // rows of 64 f32 = 32 float2
    const f32x2* __restrict__ sin_tab,
    const int*   __restrict__ tok_pos,
    f32x4*       __restrict__ out)
{
    int t = blockIdx.x * BLOCK + threadIdx.x;   // 0 .. STRIDE-1
    const int j   = t & (NF4_PER_ROW - 1);      // float4 index within row
    const int s   = t >> 5;                     // row within batch == s
    const int pos = tok_pos[s];

    const f32x2 c  = cos_tab[pos * (DK / 4) + j];
    const f32x2 sn = sin_tab[pos * (DK / 4) + j];

#pragma unroll 1
    for (int i = 0; i < ITERS; ++i, t += STRIDE) {
        const f32x4 v = x[t];
        f32x4 o;
        o.x = c.x * v.x - sn.x * v.y;
        o.y = sn.x * v.x + c.x * v.y;
        o.z = c.y * v.z - sn.y * v.w;
        o.w = sn.y * v.z + c.y * v.w;
        out[t] = o;
    }
}

extern "C" void kernel_launch(void* const* d_in, const int* in_sizes, int n_in,
                              void* d_out, int out_size, void* d_ws, size_t ws_size,
                              hipStream_t stream) {
    const f32x4* x   = (const f32x4*)d_in[0];
    const f32x2* ct  = (const f32x2*)d_in[1];
    const f32x2* st  = (const f32x2*)d_in[2];
    const int*   tp  = (const int*)d_in[3];
    f32x4*       out = (f32x4*)d_out;

    rope_f32_kernel<<<GRID, BLOCK, 0, stream>>>(x, ct, st, tp, out);
}

// Round 6
// 25.212 us; speedup vs baseline: 1.1352x; 1.0790x over previous
//
#include <hip/hip_runtime.h>

// RoPE: x (B=8, S=16384, D=128) f32, cos/sin tables (16384, 64) f32,
// token_positions (16384,) i32. Interleaved pair layout:
// out[2i]   = cos[i]*x[2i] - sin[i]*x[2i+1]
// out[2i+1] = sin[i]*x[2i] + cos[i]*x[2i+1]
//
// Block-local 2x MLP: each block owns a contiguous 512-float4 (8 KB)
// window; thread handles t and t+256 (4 KB apart -> same DRAM page
// neighborhood, both fully coalesced). Doubles in-flight loads/stores
// per thread WITHOUT the far-split pattern that regressed in R4.

typedef float f32x4 __attribute__((ext_vector_type(4)));
typedef float f32x2 __attribute__((ext_vector_type(2)));

#define S_LEN 16384
#define DK    128
#define NF4_PER_ROW (DK / 4)              // 32 float4 per row
#define BLOCK 256

__global__ __launch_bounds__(BLOCK) void rope_f32_kernel(
    const f32x4* __restrict__ x,
    const f32x2* __restrict__ cos_tab,   // rows of 64 f32 = 32 float2
    const f32x2* __restrict__ sin_tab,
    const int*   __restrict__ tok_pos,
    f32x4*       __restrict__ out)
{
    const int t0 = blockIdx.x * (2 * BLOCK) + threadIdx.x;
    const int t1 = t0 + BLOCK;

    const int j0 = t0 & (NF4_PER_ROW - 1);
    const int s0 = (t0 >> 5) & (S_LEN - 1);
    const int j1 = t1 & (NF4_PER_ROW - 1);
    const int s1 = (t1 >> 5) & (S_LEN - 1);

    const int pos0 = tok_pos[s0];
    const int pos1 = tok_pos[s1];

    const f32x4 v0 = x[t0];
    const f32x4 v1 = x[t1];
    const f32x2 c0  = cos_tab[pos0 * (DK / 4) + j0];
    const f32x2 sn0 = sin_tab[pos0 * (DK / 4) + j0];
    const f32x2 c1  = cos_tab[pos1 * (DK / 4) + j1];
    const f32x2 sn1 = sin_tab[pos1 * (DK / 4) + j1];

    f32x4 o0, o1;
    o0.x = c0.x * v0.x - sn0.x * v0.y;
    o0.y = sn0.x * v0.x + c0.x * v0.y;
    o0.z = c0.y * v0.z - sn0.y * v0.w;
    o0.w = sn0.y * v0.z + c0.y * v0.w;

    o1.x = c1.x * v1.x - sn1.x * v1.y;
    o1.y = sn1.x * v1.x + c1.x * v1.y;
    o1.z = c1.y * v1.z - sn1.y * v1.w;
    o1.w = sn1.y * v1.z + c1.y * v1.w;

    out[t0] = o0;
    out[t1] = o1;
}

extern "C" void kernel_launch(void* const* d_in, const int* in_sizes, int n_in,
                              void* d_out, int out_size, void* d_ws, size_t ws_size,
                              hipStream_t stream) {
    const f32x4* x   = (const f32x4*)d_in[0];
    const f32x2* ct  = (const f32x2*)d_in[1];
    const f32x2* st  = (const f32x2*)d_in[2];
    const int*   tp  = (const int*)d_in[3];
    f32x4*       out = (f32x4*)d_out;

    const int n_f4  = out_size / 4;                 // 4,194,304
    const int grid  = n_f4 / (2 * BLOCK);           // 8192

    rope_f32_kernel<<<grid, BLOCK, 0, stream>>>(x, ct, st, tp, out);
}